// Round 6
// baseline (263.135 us; speedup 1.0000x reference)
//
#include <hip/hip_runtime.h>
#include <cstdint>
#include <cstddef>

#define NN 2048   // nodes
#define NE 4096   // edges
#define NG 128    // graphs
#define HD 128    // hidden
#define SKM 16    // split-K blocks layers 1-4 (129 h-cols: 9 + 15x8)
#define SK0 5     // split-K blocks layer 0
#define NCH 64    // CSR sort chunks
#define CHE 64    // edges per chunk
#define WSTRIDE (40 * 4096)   // f16 per (layer, sk) fragment slab (36 steps + overrun pad)

typedef __attribute__((ext_vector_type(8))) _Float16 f16x8;
typedef __attribute__((ext_vector_type(4))) float f32x4;

#define GLOAD_LDS16(gptr, lptr)                                                          \
  __builtin_amdgcn_global_load_lds((const __attribute__((address_space(1))) unsigned int*)(gptr), \
                                   (__attribute__((address_space(3))) unsigned int*)(lptr), 16, 0, 0)

// ---------------- fused prep: hist/counts + edge-MLP h + x-pad + w2T0 + w2F ----------------
__global__ __launch_bounds__(256) void k_prep(
    const float* __restrict__ ea,
    const float* __restrict__ w1_0, const float* __restrict__ b1_0,
    const float* __restrict__ w1_s, const float* __restrict__ b1_s,
    const float* __restrict__ x,
    const float* __restrict__ w2_0, const float* __restrict__ b2_0,
    const float* __restrict__ w2s, const float* __restrict__ b2s,
    const int* __restrict__ dst, int* __restrict__ hist, int* __restrict__ counts,
    _Float16* __restrict__ hb, _Float16* __restrict__ x16,
    _Float16* __restrict__ w2T0, _Float16* __restrict__ w2F) {
  __shared__ float sld[32][128];
  const int bid = blockIdx.x, t = threadIdx.x;

  if (bid < 10240) {
    // edge MLP h for all 5 layers
    int idx = bid * 256 + t;             // l*2^19 + e*128 + c
    int c = idx & (HD - 1);
    int e = (idx >> 7) & (NE - 1);
    int l = idx >> 19;
    const float* w1 = (l == 0) ? w1_0 : (w1_s + (size_t)(l - 1) * 4 * HD);
    const float* b1 = (l == 0) ? b1_0 : (b1_s + (size_t)(l - 1) * HD);
    float4 a = *(const float4*)(ea + (size_t)e * 4);
    float v = b1[c] + a.x * w1[c] + a.y * w1[HD + c] + a.z * w1[2 * HD + c] + a.w * w1[3 * HD + c];
    hb[idx] = (_Float16)fmaxf(v, 0.f);
  } else if (bid < 10368) {
    // pad x [2048][11] f32 -> [2048][16] f16
    int idx = (bid - 10240) * 256 + t;
    int n = idx >> 4, i = idx & 15;
    x16[idx] = (_Float16)(i < 11 ? x[(size_t)n * 11 + i] : 0.f);
  } else if (bid < 10496) {
    // layer-0 weight: w2T0[o][kappa], kappa = 16k+i (i<11 valid; k=128 bias), KT0=2080
    int o = bid - 10368;
    for (int kap = t; kap < 2080; kap += 256) {
      int k = kap >> 4, i = kap & 15;
      float v = 0.f;
      if (i < 11) {
        if (k < 128) v = w2_0[(size_t)k * 1408 + i * 128 + o];
        else if (k == 128) v = b2_0[i * 128 + o];
      }
      w2T0[(size_t)o * 2080 + kap] = (_Float16)v;
    }
  } else if (bid < 12560) {
    // layers 1-4: w2F fragment-order slabs. One block per (layer, sk, step).
    int idx2 = bid - 10496;              // 0..2063 = l(4) x 516 steps
    int l = idx2 / 516;
    int r = idx2 - l * 516;
    int sk, s;
    if (r < 36) { sk = 0; s = r; } else { sk = 1 + (r - 36) / 32; s = (r - 36) & 31; }
    int nk = (sk == 0) ? 9 : 8;
    int k0 = (sk == 0) ? 0 : 9 + (sk - 1) * 8;
    int wp = s / (2 * nk);
    int rem = s - wp * 2 * nk;
    int jk = rem >> 1, wv = rem & 1;
    int k = k0 + jk;
    int ib = (wp * 2 + wv) * 32;         // i-window base
    const float* srcb = (k < 128)
        ? (w2s + ((size_t)l * 16384 + (size_t)k * 128 + ib) * 128)
        : (b2s + ((size_t)l * 128 + ib) * 128);
    float* sf = &sld[0][0];
#pragma unroll
    for (int q = 0; q < 4; ++q)
      *(float4*)&sf[t * 16 + q * 4] = *(const float4*)&srcb[t * 16 + q * 4];
    __syncthreads();
    _Float16* outp = w2F + (((size_t)l * 16 + sk) * (size_t)WSTRIDE) + (size_t)s * 4096;
#pragma unroll
    for (int j2 = 0; j2 < 2; ++j2) {
      int f = j2 * 2048 + t * 8;
      int ng = f >> 10, nt = (f >> 9) & 1, lane = (f >> 3) & 63;
      int g = lane >> 4, l16 = lane & 15;
      int o = ng * 32 + nt * 16 + l16;
      _Float16 pk[8];
#pragma unroll
      for (int j = 0; j < 8; ++j) pk[j] = (_Float16)sld[g * 8 + j][o];
      *(f16x8*)(outp + f) = *(const f16x8*)pk;
    }
  } else {
    // per-chunk histogram + per-node counts (int atomics: deterministic)
    int e = (bid - 12560) * 256 + t;
    if (e < NE) {
      int d = dst[e];
      atomicAdd(&hist[(e >> 6) * NN + d], 1);
      atomicAdd(&counts[d], 1);
    }
  }
}

// ---------------- scan -> rowptr + chunkoff + graph bounds ----------------
__global__ __launch_bounds__(1024) void k_scan2(const int* __restrict__ hist,
                                                const int* __restrict__ counts,
                                                int* __restrict__ rowptr,
                                                int* __restrict__ chunkoff,
                                                const int* __restrict__ batch,
                                                int* __restrict__ gstart) {
  __shared__ int s[NN];
  int t = threadIdx.x;
  int c0 = counts[t], c1 = counts[t + 1024];
  s[t] = c0; s[t + 1024] = c1;
  __syncthreads();
  for (int d = 1; d < NN; d <<= 1) {
    int a0 = s[t], a1 = s[t + 1024];
    int v0 = (t >= d) ? s[t - d] : 0;
    int v1 = (t + 1024 >= d) ? s[t + 1024 - d] : 0;
    __syncthreads();
    s[t] = a0 + v0; s[t + 1024] = a1 + v1;
    __syncthreads();
  }
  rowptr[t + 1] = s[t]; rowptr[t + 1025] = s[t + 1024];
  if (t == 0) rowptr[0] = 0;
  int run0 = s[t] - c0, run1 = s[t + 1024] - c1;   // exclusive prefix
  for (int c = 0; c < NCH; ++c) {
    chunkoff[c * NN + t] = run0;        run0 += hist[c * NN + t];
    chunkoff[c * NN + t + 1024] = run1; run1 += hist[c * NN + t + 1024];
  }
  if (t <= NG) {
    int lo = 0, hi = NN;
    while (lo < hi) { int mid = (lo + hi) >> 1; if (batch[mid] < t) lo = mid + 1; else hi = mid; }
    gstart[t] = lo;
  }
}

__global__ __launch_bounds__(64) void k_fill2(const int* __restrict__ dst,
                                              const int* __restrict__ chunkoff,
                                              int* __restrict__ elist) {
  __shared__ int sd[CHE];
  int c = blockIdx.x, t = threadIdx.x;
  int e = c * CHE + t;
  int dv = dst[e];
  sd[t] = dv;
  __syncthreads();
  int lrank = 0;
  for (int j = 0; j < t; ++j) lrank += (sd[j] == dv) ? 1 : 0;
  elist[chunkoff[c * NN + dv] + lrank] = e;   // stable order -> deterministic sums
}

// ---------------- layer-0 MFMA GEMM (R5 structure, small) ----------------
__global__ __launch_bounds__(256, 2) void k_mma0(
    const _Float16* __restrict__ xh,   // [NN][16] f16
    const _Float16* __restrict__ hb,   // [NE][128] f16 (layer 0)
    const _Float16* __restrict__ w2T,  // [128][2080]
    const int* __restrict__ src,
    _Float16* __restrict__ msgp) {
  constexpr int KT = 2080;
  __shared__ _Float16 Bs[2][4096];
  __shared__ _Float16 hTl[26][128];

  const int tid = threadIdx.x;
  const int e0 = blockIdx.x * 128;
  const int w = tid >> 6, l = tid & 63, l16 = l & 15, g = l >> 4;

  const int k0 = blockIdx.y * 13, nk = 13;
  const int kb = k0 * 2;

  int nd[8];
#pragma unroll
  for (int mt = 0; mt < 8; ++mt) nd[mt] = src[e0 + mt * 16 + l16];

  for (int idx = tid; idx < 26 * 128; idx += 256) {
    int kk = idx >> 7, m = idx & 127;
    int k = kb + kk;
    _Float16 v;
    if (k < 128) v = hb[(size_t)(e0 + m) * 128 + k];
    else v = (k == 128) ? (_Float16)1.0f : (_Float16)0.0f;
    hTl[kk][m] = v;
  }

  f16x8 xr[8];
#pragma unroll
  for (int mt = 0; mt < 8; ++mt)
    xr[mt] = *(const f16x8*)(xh + (size_t)nd[mt] * 16 + (g & 1) * 8);

  auto stageB = [&](int buf, int c) {
    const int kap0 = c * 32;
#pragma unroll
    for (int j2 = 0; j2 < 2; ++j2) {
      int ntg = w * 2 + j2;
      const _Float16* gp = w2T + (size_t)(ntg * 16 + l16) * KT + kap0 + g * 8;
      GLOAD_LDS16(gp, &Bs[buf][(w * 128 + j2 * 64) * 8]);
    }
  };

  stageB(0, k0);
  __syncthreads();

  f32x4 acc[8][2];
#pragma unroll
  for (int mt = 0; mt < 8; ++mt)
#pragma unroll
    for (int jj = 0; jj < 2; ++jj) acc[mt][jj] = (f32x4){0.f, 0.f, 0.f, 0.f};

  int buf = 0;
  for (int j = 0; j < nk; ++j) {
    if (j + 1 < nk) {
      stageB(buf ^ 1, k0 + j + 1);
      asm volatile("s_waitcnt vmcnt(2)" ::: "memory");
    } else {
      asm volatile("s_waitcnt vmcnt(0)" ::: "memory");
    }
    __builtin_amdgcn_sched_barrier(0);

    f16x8 bv0 = *(const f16x8*)&Bs[buf][(size_t)(w * 2 + 0) * 512 + l * 8];
    f16x8 bv1 = *(const f16x8*)&Bs[buf][(size_t)(w * 2 + 1) * 512 + l * 8];
#pragma unroll
    for (int mt = 0; mt < 8; ++mt) {
      _Float16 hh = hTl[2 * j + (g >> 1)][mt * 16 + l16];
      f16x8 hv = {hh, hh, hh, hh, hh, hh, hh, hh};
      f16x8 av = xr[mt] * hv;
      acc[mt][0] = __builtin_amdgcn_mfma_f32_16x16x32_f16(av, bv0, acc[mt][0], 0, 0, 0);
      acc[mt][1] = __builtin_amdgcn_mfma_f32_16x16x32_f16(av, bv1, acc[mt][1], 0, 0, 0);
    }
    buf ^= 1;
    __syncthreads();
  }

  _Float16* mp = msgp + ((size_t)blockIdx.y * NE + e0) * 128;
#pragma unroll
  for (int mt = 0; mt < 8; ++mt)
#pragma unroll
    for (int jj = 0; jj < 2; ++jj)
#pragma unroll
      for (int r = 0; r < 4; ++r) {
        int row = mt * 16 + 4 * g + r;
        mp[(size_t)row * 128 + w * 32 + jj * 16 + l16] = (_Float16)acc[mt][jj][r];
      }
}

// ---------------- layers 1-4 MFMA GEMM: B streamed from L2 into registers ----------------
// Block: 256 edges x 128 out; 8 waves = 2mg(128 rows) x 4ng(32 cols); wave tile
// mt=8 x nt=2. A (x*h) entirely in registers (xw per half-pass), h from 5KB LDS,
// B fragments loaded as coalesced 1KB register streams from fragment-ordered w2F
// (L2-resident slab, same-sk blocks share an XCD via bid=eb*16+sk). K-loop has
// ZERO barriers and ZERO LDS B-traffic; 1-jk-ahead ping-pong prefetch (~2 steps
// = ~450cy) covers L2 latency; compiler manages waitcnt for register deps.
__global__ __launch_bounds__(512, 2) void k_mma3(
    const _Float16* __restrict__ xh,    // [NN][128]
    const _Float16* __restrict__ hb,    // [NE][128] (this layer)
    const _Float16* __restrict__ w2Fl,  // fragment slabs for this layer
    const int* __restrict__ src,
    _Float16* __restrict__ msgp) {      // [SK][NE][128]
  __shared__ _Float16 h_lds[256][10];

  const int tid = threadIdx.x;
  const int w = tid >> 6, l = tid & 63, l16 = l & 15, g = l >> 4;
  const int mg = w >> 2, ng = w & 3;
  const int bid = blockIdx.x;
  const int eb = bid >> 4, sk = bid & 15;
  const int e0 = eb * 256;

  const int nk = (sk == 0) ? 9 : 8;
  const int k0 = (sk == 0) ? 0 : 9 + (sk - 1) * 8;

  // ---- stage h table [256 rows][nk cols] (scalar, L2-resident) ----
  for (int i = tid; i < (nk << 8); i += 512) {
    int kk = i >> 8, m = i & 255;
    int k = k0 + kk;
    h_lds[m][kk] = (k < 128) ? hb[(size_t)(e0 + m) * 128 + k] : (_Float16)1.0f;
  }

  // ---- per-lane node ids for this wave's 8 M-tiles ----
  int nd[8];
#pragma unroll
  for (int mt = 0; mt < 8; ++mt) nd[mt] = src[e0 + mg * 128 + mt * 16 + l16];
  __syncthreads();   // h_lds ready (the only barrier)

  const _Float16* bw = w2Fl + (size_t)sk * WSTRIDE + ng * 1024 + (size_t)l * 8;

  f32x4 acc[8][2];
#pragma unroll
  for (int mt = 0; mt < 8; ++mt) {
    acc[mt][0] = (f32x4){0.f, 0.f, 0.f, 0.f};
    acc[mt][1] = (f32x4){0.f, 0.f, 0.f, 0.f};
  }

#define LOAD4(v0, v1, v2, v3, pairidx)                                   \
  {                                                                      \
    const _Float16* q_ = bw + (size_t)(pairidx) * 8192;                  \
    v0 = *(const f16x8*)(q_);                                            \
    v1 = *(const f16x8*)(q_ + 512);                                      \
    v2 = *(const f16x8*)(q_ + 4096);                                     \
    v3 = *(const f16x8*)(q_ + 4608);                                     \
  }

#define BODY(jk_, b0, b1, b2, b3)                                        \
  {                                                                      \
    _Float16 hv_[8];                                                     \
    _Pragma("unroll")                                                    \
    for (int mt = 0; mt < 8; ++mt)                                       \
      hv_[mt] = h_lds[mg * 128 + mt * 16 + l16][jk_];                    \
    _Pragma("unroll")                                                    \
    for (int mt = 0; mt < 8; ++mt) {                                     \
      _Float16 hh = hv_[mt];                                             \
      f16x8 hs = {hh, hh, hh, hh, hh, hh, hh, hh};                       \
      f16x8 av = xw0[mt] * hs;                                           \
      acc[mt][0] = __builtin_amdgcn_mfma_f32_16x16x32_f16(av, b0, acc[mt][0], 0, 0, 0); \
      acc[mt][1] = __builtin_amdgcn_mfma_f32_16x16x32_f16(av, b1, acc[mt][1], 0, 0, 0); \
    }                                                                    \
    _Pragma("unroll")                                                    \
    for (int mt = 0; mt < 8; ++mt) {                                     \
      _Float16 hh = hv_[mt];                                             \
      f16x8 hs = {hh, hh, hh, hh, hh, hh, hh, hh};                       \
      f16x8 av = xw1[mt] * hs;                                           \
      acc[mt][0] = __builtin_amdgcn_mfma_f32_16x16x32_f16(av, b2, acc[mt][0], 0, 0, 0); \
      acc[mt][1] = __builtin_amdgcn_mfma_f32_16x16x32_f16(av, b3, acc[mt][1], 0, 0, 0); \
    }                                                                    \
  }

  for (int wp = 0; wp < 2; ++wp) {
    // per-half-pass x register cache: 8 rows x 2 windows
    f16x8 xw0[8], xw1[8];
#pragma unroll
    for (int mt = 0; mt < 8; ++mt) {
      const _Float16* xp = xh + (size_t)nd[mt] * 128 + (wp * 2) * 32 + g * 8;
      xw0[mt] = *(const f16x8*)(xp);
      xw1[mt] = *(const f16x8*)(xp + 32);
    }
    const int pb = wp * nk;
    f16x8 c0, c1, c2, c3, n0, n1, n2, n3;
    LOAD4(c0, c1, c2, c3, pb);
    int jk = 0;
    while (true) {
      LOAD4(n0, n1, n2, n3, pb + jk + 1);   // may overrun into pad: never consumed
      BODY(jk, c0, c1, c2, c3);
      ++jk;
      if (jk >= nk) break;
      LOAD4(c0, c1, c2, c3, pb + jk + 1);
      BODY(jk, n0, n1, n2, n3);
      ++jk;
      if (jk >= nk) break;
    }
  }
#undef LOAD4
#undef BODY

  // ---- epilogue: C/D row = 4g + r, col = l16 ----
  _Float16* mp = msgp + ((size_t)sk * NE + e0) * 128;
#pragma unroll
  for (int mt = 0; mt < 8; ++mt)
#pragma unroll
    for (int nt = 0; nt < 2; ++nt)
#pragma unroll
      for (int r = 0; r < 4; ++r) {
        int row = mg * 128 + mt * 16 + 4 * g + r;
        int col = ng * 32 + nt * 16 + l16;
        mp[(size_t)row * 128 + col] = (_Float16)acc[mt][nt][r];
      }
}

// ---------------- fused: split-K reduce + scatter-mean + root + BN + ReLU (+res) ----------------
// 512 blocks x 256 thr; 4 nodes/block (2 parallel x 2 passes); root stays L1-hot;
// 4-way ILP partial sums break the serial FMA chain.
template <int INR, int NSK, bool RES>
__global__ __launch_bounds__(256) void k_au2(
    const _Float16* __restrict__ msgp, const int* __restrict__ rowptr,
    const int* __restrict__ elist, const float* __restrict__ xin,
    const float* __restrict__ root, const float* __restrict__ bias,
    const float* __restrict__ bg, const float* __restrict__ bb,
    const float* __restrict__ bm, const float* __restrict__ bv,
    const float* __restrict__ h_prev, float* __restrict__ h_out,
    _Float16* __restrict__ h_out_h) {
  __shared__ float xr[2][INR];
  const int nb = blockIdx.x;
  const int sub = threadIdx.x >> 7, col = threadIdx.x & 127;
  for (int p = 0; p < 2; ++p) {
    int n = nb * 4 + p * 2 + sub;
    if (col < INR) xr[sub][col] = xin[(size_t)n * INR + col];
    __syncthreads();
    int beg = rowptr[n], end = rowptr[n + 1];
    float v = 0.f;
    for (int j = beg; j < end; ++j) {
      int e = elist[j];
#pragma unroll
      for (int s = 0; s < NSK; ++s) v += (float)msgp[((size_t)s * NE + e) * HD + col];
    }
    v /= fmaxf((float)(end - beg), 1.f);
    float acc = v + bias[col];
    if constexpr (INR == 128) {
      float a0 = 0.f, a1 = 0.f, a2 = 0.f, a3 = 0.f;
#pragma unroll 4
      for (int k = 0; k < 128; k += 4) {
        a0 += xr[sub][k + 0] * root[(size_t)(k + 0) * HD + col];
        a1 += xr[sub][k + 1] * root[(size_t)(k + 1) * HD + col];
        a2 += xr[sub][k + 2] * root[(size_t)(k + 2) * HD + col];
        a3 += xr[sub][k + 3] * root[(size_t)(k + 3) * HD + col];
      }
      acc += (a0 + a1) + (a2 + a3);
    } else {
#pragma unroll
      for (int k = 0; k < INR; ++k) acc += xr[sub][k] * root[(size_t)k * HD + col];
    }
    float bn = (acc - bm[col]) * rsqrtf(bv[col] + 1e-5f) * bg[col] + bb[col];
    float r = fmaxf(bn, 0.f);
    float val = RES ? (h_prev[(size_t)n * HD + col] + r) : r;
    h_out[(size_t)n * HD + col] = val;
    h_out_h[(size_t)n * HD + col] = (_Float16)val;
    __syncthreads();
  }
}

// ---------------- fused global mean pool + readout MLP ----------------
__global__ void k_poolread(const float* __restrict__ h, const int* __restrict__ gstart,
                           const float* __restrict__ w1, const float* __restrict__ b1,
                           const float* __restrict__ w2, const float* __restrict__ b2,
                           float* __restrict__ out) {
  int g = blockIdx.x, t = threadIdx.x;  // 128 threads
  __shared__ float row[HD];
  int beg = gstart[g], end = gstart[g + 1];
  float v = 0.f;
  for (int n = beg; n < end; ++n) v += h[(size_t)n * HD + t];
  row[t] = v / fmaxf((float)(end - beg), 1.f);
  __syncthreads();
  if (t < 64) {
    float acc = b1[t];
#pragma unroll 8
    for (int k = 0; k < HD; ++k) acc += row[k] * w1[(size_t)k * 64 + t];
    float vv = fmaxf(acc, 0.f) * w2[t];
#pragma unroll
    for (int off = 32; off > 0; off >>= 1) vv += __shfl_down(vv, off);
    if (t == 0) out[g] = vv + b2[0];
  }
}

extern "C" void kernel_launch(void* const* d_in, const int* in_sizes, int n_in,
                              void* d_out, int out_size, void* d_ws, size_t ws_size,
                              hipStream_t stream) {
  const float* x      = (const float*)d_in[0];
  const float* ea     = (const float*)d_in[1];
  const int*   eidx   = (const int*)d_in[2];
  const int*   batch  = (const int*)d_in[3];
  const float* w1_0   = (const float*)d_in[4];
  const float* b1_0   = (const float*)d_in[5];
  const float* w2_0   = (const float*)d_in[6];
  const float* b2_0   = (const float*)d_in[7];
  const float* root_0 = (const float*)d_in[8];
  const float* bias_0 = (const float*)d_in[9];
  const float* bn_g0  = (const float*)d_in[10];
  const float* bn_b0  = (const float*)d_in[11];
  const float* bn_m0  = (const float*)d_in[12];
  const float* bn_v0  = (const float*)d_in[13];
  const float* w1_s   = (const float*)d_in[14];
  const float* b1_s   = (const float*)d_in[15];
  const float* w2_s   = (const float*)d_in[16];
  const float* b2_s   = (const float*)d_in[17];
  const float* root_s = (const float*)d_in[18];
  const float* bias_s = (const float*)d_in[19];
  const float* bn_gs  = (const float*)d_in[20];
  const float* bn_bs  = (const float*)d_in[21];
  const float* bn_ms  = (const float*)d_in[22];
  const float* bn_vs  = (const float*)d_in[23];
  const float* lin1_w = (const float*)d_in[24];
  const float* lin1_b = (const float*)d_in[25];
  const float* lin2_w = (const float*)d_in[26];
  const float* lin2_b = (const float*)d_in[27];
  float* out = (float*)d_out;

  char* wsb = (char*)d_ws;
  size_t off = 0;
  auto alloc = [&](size_t bytes) { void* p = wsb + off; off = (off + bytes + 255) & ~(size_t)255; return p; };
  int*      hist     = (int*)alloc((size_t)NCH * NN * 4);   // hist+counts contiguous: one memset
  int*      counts   = (int*)alloc(NN * 4);
  int*      rowptr   = (int*)alloc((NN + 4) * 4);
  int*      elist    = (int*)alloc(NE * 4);
  int*      gstart   = (int*)alloc((NG + 4) * 4);
  int*      chunkoff = (int*)alloc((size_t)NCH * NN * 4);
  _Float16* hbf      = (_Float16*)alloc((size_t)5 * NE * HD * 2);
  _Float16* x16      = (_Float16*)alloc((size_t)NN * 16 * 2);
  _Float16* w2T0     = (_Float16*)alloc((size_t)128 * 2080 * 2);
  _Float16* w2F      = (_Float16*)alloc((size_t)4 * 16 * WSTRIDE * 2);
  float*    hnA      = (float*)alloc((size_t)NN * HD * 4);
  float*    hnB      = (float*)alloc((size_t)NN * HD * 4);
  _Float16* hnAh     = (_Float16*)alloc((size_t)NN * HD * 2);
  _Float16* hnBh     = (_Float16*)alloc((size_t)NN * HD * 2);
  _Float16* msgp     = (_Float16*)alloc((size_t)SKM * NE * HD * 2);

  const int* src = eidx;
  const int* dstp = eidx + NE;

  hipMemsetAsync(hist, 0, ((size_t)NCH * NN + NN) * 4, stream);
  k_prep<<<dim3(12576), 256, 0, stream>>>(ea, w1_0, b1_0, w1_s, b1_s, x,
                                          w2_0, b2_0, w2_s, b2_s,
                                          dstp, hist, counts, hbf, x16, w2T0, w2F);
  k_scan2<<<1, 1024, 0, stream>>>(hist, counts, rowptr, chunkoff, batch, gstart);
  k_fill2<<<dim3(NCH), 64, 0, stream>>>(dstp, chunkoff, elist);

  // layer 0
  k_mma0<<<dim3(NE / 128, SK0), 256, 0, stream>>>(x16, hbf, w2T0, src, msgp);
  k_au2<11, SK0, false><<<dim3(512), 256, 0, stream>>>(msgp, rowptr, elist, x, root_0, bias_0,
                                                       bn_g0, bn_b0, bn_m0, bn_v0,
                                                       nullptr, hnA, hnAh);

  float* cur = hnA;  _Float16* curh = hnAh;
  float* nxt = hnB;  _Float16* nxth = hnBh;
  for (int l = 1; l <= 4; ++l) {
    const _Float16* w2Fl = w2F + (size_t)(l - 1) * 16 * WSTRIDE;
    k_mma3<<<dim3(256), 512, 0, stream>>>(curh, hbf + (size_t)l * NE * HD, w2Fl, src, msgp);
    k_au2<128, SKM, true><<<dim3(512), 256, 0, stream>>>(
        msgp, rowptr, elist, cur,
        root_s + (size_t)(l - 1) * HD * HD, bias_s + (size_t)(l - 1) * HD,
        bn_gs + (size_t)(l - 1) * HD, bn_bs + (size_t)(l - 1) * HD,
        bn_ms + (size_t)(l - 1) * HD, bn_vs + (size_t)(l - 1) * HD,
        cur, nxt, nxth);
    float* tf = cur; cur = nxt; nxt = tf;
    _Float16* th = curh; curh = nxth; nxth = th;
  }

  k_poolread<<<NG, HD, 0, stream>>>(cur, gstart, lin1_w, lin1_b, lin2_w, lin2_b, out);
}